// Round 1
// baseline (12503.598 us; speedup 1.0000x reference)
//
#include <hip/hip_runtime.h>
#include <math.h>

// Performer (FAVOR+) forward, 6 layers, fp32 baseline.
// B=8 N=4096 DIM=3 H=3 DH=128 INNER=384 M=620 FF=12
#define B_ 8
#define N_ 4096
#define H_ 3
#define DH_ 128
#define INNER_ 384
#define M_ 620
#define DEPTH_ 6
#define BH_ 24

static constexpr float DN_ = 0.29730177875068026f;     // 128^-0.25
static constexpr float RATIO_ = 0.04016096644512494f;  // 620^-0.5
static constexpr float EPS_ = 1e-4f;

__device__ __forceinline__ float4 ldg4(const float* p) { return *(const float4*)p; }

// ---------------------------------------------------------------- copy
__global__ void k_copy(const float* __restrict__ s, float* __restrict__ d, int n) {
  int i = blockIdx.x * 256 + threadIdx.x;
  if (i < n) d[i] = s[i];
}

// ------------------------------------------------- LN1 + QKV projection
// grid B*N blocks, 384 threads. q,k stored pre-scaled by DN_.
__global__ __launch_bounds__(384) void k_ln_qkv(
    const float* __restrict__ x, const float* __restrict__ Wq,
    const float* __restrict__ Wk, const float* __restrict__ Wv,
    const float* __restrict__ g1, const float* __restrict__ b1,
    float* __restrict__ q, float* __restrict__ k, float* __restrict__ v) {
  int token = blockIdx.x;
  int b = token >> 12, n = token & 4095;
  int c = threadIdx.x;
  float x0 = x[(size_t)token * 3 + 0];
  float x1 = x[(size_t)token * 3 + 1];
  float x2 = x[(size_t)token * 3 + 2];
  float mu = (x0 + x1 + x2) * (1.f / 3.f);
  float d0 = x0 - mu, d1 = x1 - mu, d2 = x2 - mu;
  float rs = rsqrtf((d0 * d0 + d1 * d1 + d2 * d2) * (1.f / 3.f) + 1e-5f);
  float h0 = d0 * rs * g1[0] + b1[0];
  float h1 = d1 * rs * g1[1] + b1[1];
  float h2 = d2 * rs * g1[2] + b1[2];
  float qv = h0 * Wq[c] + h1 * Wq[INNER_ + c] + h2 * Wq[2 * INNER_ + c];
  float kv = h0 * Wk[c] + h1 * Wk[INNER_ + c] + h2 * Wk[2 * INNER_ + c];
  float vv = h0 * Wv[c] + h1 * Wv[INNER_ + c] + h2 * Wv[2 * INNER_ + c];
  int hh = c >> 7, dh = c & 127;
  size_t idx = (((size_t)(b * H_ + hh)) * N_ + n) * DH_ + dh;
  q[idx] = qv * DN_;
  k[idx] = kv * DN_;
  v[idx] = vv;
}

// ------------------------------------------------- key-side global max
// grid (10 mt, 64 nt, 24 bh), 256 threads. dd = k' @ proj^T, block max out.
__global__ __launch_bounds__(256) void k_kmax(
    const float* __restrict__ kbuf, const float* __restrict__ proj,
    float* __restrict__ blkmax) {
  int mt = blockIdx.x, nt = blockIdx.y, bh = blockIdx.z;
  __shared__ float As[64][132];
  __shared__ float Bs[64][132];
  __shared__ float red[256];
  const float* kp = kbuf + (((size_t)bh) * N_ + nt * 64) * DH_;
  int mrem = M_ - mt * 64; if (mrem > 64) mrem = 64;
  for (int t = threadIdx.x; t < 64 * 32; t += 256) {
    int r = t >> 5, c4 = t & 31;
    *(float4*)(&As[r][c4 * 4]) = ldg4(kp + (size_t)r * DH_ + c4 * 4);
    float4 z = make_float4(0.f, 0.f, 0.f, 0.f);
    *(float4*)(&Bs[r][c4 * 4]) =
        (r < mrem) ? ldg4(proj + ((size_t)(mt * 64 + r)) * DH_ + c4 * 4) : z;
  }
  __syncthreads();
  int tr = threadIdx.x >> 4, tc = threadIdx.x & 15;
  int r0 = tr * 4, c0 = tc * 4;
  float acc[4][4] = {};
  for (int d = 0; d < DH_; d += 4) {
    float4 a[4], bb[4];
#pragma unroll
    for (int i = 0; i < 4; ++i) a[i] = *(const float4*)(&As[r0 + i][d]);
#pragma unroll
    for (int j = 0; j < 4; ++j) bb[j] = *(const float4*)(&Bs[c0 + j][d]);
#pragma unroll
    for (int i = 0; i < 4; ++i)
#pragma unroll
      for (int j = 0; j < 4; ++j)
        acc[i][j] += a[i].x * bb[j].x + a[i].y * bb[j].y + a[i].z * bb[j].z + a[i].w * bb[j].w;
  }
  float mx = -INFINITY;
#pragma unroll
  for (int i = 0; i < 4; ++i)
#pragma unroll
    for (int j = 0; j < 4; ++j)
      if (c0 + j < mrem) mx = fmaxf(mx, acc[i][j]);
  red[threadIdx.x] = mx;
  __syncthreads();
  for (int s = 128; s > 0; s >>= 1) {
    if (threadIdx.x < (unsigned)s) red[threadIdx.x] = fmaxf(red[threadIdx.x], red[threadIdx.x + s]);
    __syncthreads();
  }
  if (threadIdx.x == 0) blkmax[((size_t)bh * 64 + nt) * 10 + mt] = red[0];
}

__global__ __launch_bounds__(256) void k_kmax_reduce(
    const float* __restrict__ blkmax, float* __restrict__ mx) {
  int bh = blockIdx.x;
  __shared__ float red[256];
  float m = -INFINITY;
  for (int i = threadIdx.x; i < 640; i += 256) m = fmaxf(m, blkmax[(size_t)bh * 640 + i]);
  red[threadIdx.x] = m;
  __syncthreads();
  for (int s = 128; s > 0; s >>= 1) {
    if (threadIdx.x < (unsigned)s) red[threadIdx.x] = fmaxf(red[threadIdx.x], red[threadIdx.x + s]);
    __syncthreads();
  }
  if (threadIdx.x == 0) mx[bh] = red[0];
}

// ---------------------------------------- key features -> ctx partials
// grid (2 ns, 10 mt, 24 bh), 256 threads.
// Accumulates C[m,d] = sum_n exp(dd-diag-mx) * v[n,d], s[m] = sum_n exp(...).
// EPS terms factored out (added in finalize).
__global__ __launch_bounds__(256) void k_kp_ctx(
    const float* __restrict__ kbuf, const float* __restrict__ vbuf,
    const float* __restrict__ proj, const float* __restrict__ mxbuf,
    float* __restrict__ Cpart, float* __restrict__ spart) {
  int ns = blockIdx.x, mt = blockIdx.y, bh = blockIdx.z;
  __shared__ float Ps[64][132];
  __shared__ float Ks[32][132];
  __shared__ float Vs[32][132];
  __shared__ float Es[32][68];
  __shared__ float diag[32];
  int mrem = M_ - mt * 64; if (mrem > 64) mrem = 64;
  for (int t = threadIdx.x; t < 64 * 32; t += 256) {
    int r = t >> 5, c4 = t & 31;
    float4 z = make_float4(0.f, 0.f, 0.f, 0.f);
    *(float4*)(&Ps[r][c4 * 4]) =
        (r < mrem) ? ldg4(proj + ((size_t)(mt * 64 + r)) * DH_ + c4 * 4) : z;
  }
  float mxv = mxbuf[bh];
  float ctx_acc[4][8] = {};
  float s_acc = 0.f;
  const float* kb = kbuf + ((size_t)bh * N_ + ns * 2048) * DH_;
  const float* vb = vbuf + ((size_t)bh * N_ + ns * 2048) * DH_;
  const int rowg = threadIdx.x >> 4;  // dd: 2 rows
  const int colg = threadIdx.x & 15;  // dd: 4 cols
  const int tm = threadIdx.x >> 4;    // ctx: 4 m
  const int td = threadIdx.x & 15;    // ctx: 8 d
  for (int ch = 0; ch < 64; ++ch) {
    const float* kc = kb + (size_t)ch * 32 * DH_;
    const float* vc = vb + (size_t)ch * 32 * DH_;
    __syncthreads();
    for (int t = threadIdx.x; t < 32 * 32; t += 256) {
      int r = t >> 5, c4 = t & 31;
      *(float4*)(&Ks[r][c4 * 4]) = ldg4(kc + (size_t)r * DH_ + c4 * 4);
      *(float4*)(&Vs[r][c4 * 4]) = ldg4(vc + (size_t)r * DH_ + c4 * 4);
    }
    __syncthreads();
    if (threadIdx.x < 32) {
      float s = 0.f;
      for (int d = 0; d < DH_; ++d) { float kv = Ks[threadIdx.x][d]; s += kv * kv; }
      diag[threadIdx.x] = 0.5f * s;
    }
    __syncthreads();
    float dd[2][4] = {};
    for (int d = 0; d < DH_; d += 4) {
      float4 a0 = *(const float4*)(&Ks[rowg * 2 + 0][d]);
      float4 a1 = *(const float4*)(&Ks[rowg * 2 + 1][d]);
#pragma unroll
      for (int j = 0; j < 4; ++j) {
        float4 bv = *(const float4*)(&Ps[colg * 4 + j][d]);
        dd[0][j] += a0.x * bv.x + a0.y * bv.y + a0.z * bv.z + a0.w * bv.w;
        dd[1][j] += a1.x * bv.x + a1.y * bv.y + a1.z * bv.z + a1.w * bv.w;
      }
    }
#pragma unroll
    for (int i = 0; i < 2; ++i)
#pragma unroll
      for (int j = 0; j < 4; ++j) {
        int r = rowg * 2 + i, c = colg * 4 + j;
        Es[r][c] = (c < mrem) ? expf(dd[i][j] - diag[r] - mxv) : 0.f;
      }
    __syncthreads();
    if (threadIdx.x < 64) {
      float s = 0.f;
#pragma unroll 8
      for (int n = 0; n < 32; ++n) s += Es[n][threadIdx.x];
      s_acc += s;
    }
    for (int n = 0; n < 32; ++n) {
      float4 e4 = *(const float4*)(&Es[n][tm * 4]);
      float4 v0 = *(const float4*)(&Vs[n][td * 8]);
      float4 v1 = *(const float4*)(&Vs[n][td * 8 + 4]);
      float ev[4] = {e4.x, e4.y, e4.z, e4.w};
      float vv[8] = {v0.x, v0.y, v0.z, v0.w, v1.x, v1.y, v1.z, v1.w};
#pragma unroll
      for (int i = 0; i < 4; ++i)
#pragma unroll
        for (int j = 0; j < 8; ++j) ctx_acc[i][j] += ev[i] * vv[j];
    }
  }
  float* Cp = Cpart + ((size_t)ns * BH_ + bh) * M_ * DH_;
#pragma unroll
  for (int i = 0; i < 4; ++i) {
    int ml = tm * 4 + i;
    if (ml < mrem) {
#pragma unroll
      for (int j = 0; j < 8; ++j)
        Cp[((size_t)(mt * 64 + ml)) * DH_ + td * 8 + j] = ctx_acc[i][j];
    }
  }
  if (threadIdx.x < 64 && threadIdx.x < mrem)
    spart[((size_t)ns * BH_ + bh) * M_ + mt * 64 + threadIdx.x] = s_acc;
}

// v column-sum partials: grid (8 ns, 24 bh), 128 threads
__global__ __launch_bounds__(128) void k_vsum(
    const float* __restrict__ vbuf, float* __restrict__ vsp) {
  int ns = blockIdx.x, bh = blockIdx.y, d = threadIdx.x;
  const float* vb = vbuf + ((size_t)bh * N_ + ns * 512) * DH_;
  float s = 0.f;
  for (int n = 0; n < 512; ++n) s += vb[(size_t)n * DH_ + d];
  vsp[((size_t)ns * BH_ + bh) * DH_ + d] = s;
}

// finalize ctx / k_sum (+EPS terms, ratio), plus ctxsum[d], ksumtot
__global__ __launch_bounds__(128) void k_finalize(
    const float* __restrict__ Cpart, const float* __restrict__ spart,
    const float* __restrict__ vsp,
    float* __restrict__ ctx, float* __restrict__ ksum,
    float* __restrict__ ctxsum, float* __restrict__ ksumtot) {
  int bh = blockIdx.x, d = threadIdx.x;
  float vsv = 0.f;
#pragma unroll
  for (int ns = 0; ns < 8; ++ns) vsv += vsp[((size_t)ns * BH_ + bh) * DH_ + d];
  vsv *= EPS_;
  const float* c0 = Cpart + (size_t)bh * M_ * DH_;
  const float* c1 = c0 + (size_t)BH_ * M_ * DH_;
  float* cx = ctx + (size_t)bh * M_ * DH_;
  float csum = 0.f;
  for (int m = 0; m < M_; ++m) {
    float c = RATIO_ * (c0[(size_t)m * DH_ + d] + c1[(size_t)m * DH_ + d] + vsv);
    cx[(size_t)m * DH_ + d] = c;
    csum += c;
  }
  ctxsum[bh * DH_ + d] = csum;
  __shared__ float red[128];
  float kt = 0.f;
  for (int m = d; m < M_; m += 128) {
    float ks = RATIO_ * (spart[(size_t)bh * M_ + m] + spart[(size_t)BH_ * M_ + bh * M_ + m] +
                         EPS_ * (float)N_);
    ksum[bh * M_ + m] = ks;
    kt += ks;
  }
  red[d] = kt;
  __syncthreads();
  for (int s = 64; s > 0; s >>= 1) {
    if (d < s) red[d] += red[d + s];
    __syncthreads();
  }
  if (d == 0) ksumtot[bh] = red[0];
}

// ------------------------- query side: online softmax + qp@ctx, in place
// grid (64 nt, 24 bh), 256 threads. Overwrites qbuf rows with attn out.
__global__ __launch_bounds__(256) void k_q_attn(
    float* __restrict__ qbuf, const float* __restrict__ proj,
    const float* __restrict__ ctx, const float* __restrict__ ksum,
    const float* __restrict__ ctxsum, const float* __restrict__ ksumtot) {
  int nt = blockIdx.x, bh = blockIdx.y;
  __shared__ float Qs[64][132];
  __shared__ float Ps[32][132];
  __shared__ float Cs[32][132];
  __shared__ float Es[64][36];
  __shared__ float diag[64], mxl[64], fsl[64], denl[64], ksl[32];
  float* qb = qbuf + (((size_t)bh) * N_ + nt * 64) * DH_;
  const float* cb = ctx + ((size_t)bh) * M_ * DH_;
  const float* kb = ksum + (size_t)bh * M_;
  for (int t = threadIdx.x; t < 64 * 32; t += 256) {
    int r = t >> 5, c4 = t & 31;
    *(float4*)(&Qs[r][c4 * 4]) = ldg4(qb + (size_t)r * DH_ + c4 * 4);
  }
  __syncthreads();
  if (threadIdx.x < 64) {
    float s = 0.f;
    for (int d = 0; d < DH_; ++d) { float qv = Qs[threadIdx.x][d]; s += qv * qv; }
    diag[threadIdx.x] = 0.5f * s;
    mxl[threadIdx.x] = -INFINITY;
    denl[threadIdx.x] = 0.f;
  }
  float acc[4][8] = {};
  const int rowg = threadIdx.x >> 3;  // dd: 2 rows of 64
  const int colg = threadIdx.x & 7;   // dd: 4 cols of 32
  const int tn = threadIdx.x >> 4;    // acc: 4 rows
  const int td = threadIdx.x & 15;    // acc: 8 d
  for (int mc = 0; mc < 20; ++mc) {
    int m0 = mc * 32;
    int mrem = M_ - m0; if (mrem > 32) mrem = 32;
    __syncthreads();
    for (int t = threadIdx.x; t < 32 * 32; t += 256) {
      int r = t >> 5, c4 = t & 31;
      float4 z = make_float4(0.f, 0.f, 0.f, 0.f);
      *(float4*)(&Ps[r][c4 * 4]) =
          (r < mrem) ? ldg4(proj + ((size_t)(m0 + r)) * DH_ + c4 * 4) : z;
      *(float4*)(&Cs[r][c4 * 4]) =
          (r < mrem) ? ldg4(cb + ((size_t)(m0 + r)) * DH_ + c4 * 4) : z;
    }
    if (threadIdx.x < 32) ksl[threadIdx.x] = (threadIdx.x < mrem) ? kb[m0 + threadIdx.x] : 0.f;
    __syncthreads();
    float dd[2][4] = {};
    for (int d = 0; d < DH_; d += 4) {
      float4 a0 = *(const float4*)(&Qs[rowg * 2 + 0][d]);
      float4 a1 = *(const float4*)(&Qs[rowg * 2 + 1][d]);
#pragma unroll
      for (int j = 0; j < 4; ++j) {
        float4 bv = *(const float4*)(&Ps[colg * 4 + j][d]);
        dd[0][j] += a0.x * bv.x + a0.y * bv.y + a0.z * bv.z + a0.w * bv.w;
        dd[1][j] += a1.x * bv.x + a1.y * bv.y + a1.z * bv.z + a1.w * bv.w;
      }
    }
#pragma unroll
    for (int i = 0; i < 2; ++i)
#pragma unroll
      for (int j = 0; j < 4; ++j)
        Es[rowg * 2 + i][colg * 4 + j] = (colg * 4 + j < mrem) ? dd[i][j] : -INFINITY;
    __syncthreads();
    if (threadIdx.x < 64) {
      float cm = -INFINITY;
#pragma unroll 8
      for (int c = 0; c < 32; ++c) cm = fmaxf(cm, Es[threadIdx.x][c]);
      float om = mxl[threadIdx.x];
      float nm = fmaxf(om, cm);
      mxl[threadIdx.x] = nm;
      fsl[threadIdx.x] = expf(om - nm);  // 0 on first chunk (om = -inf)
    }
    __syncthreads();
    for (int t = threadIdx.x; t < 64 * 32; t += 256) {
      int r = t >> 5, c = t & 31;
      float e = Es[r][c];
      Es[r][c] = (c < mrem) ? expf(e - diag[r] - mxl[r]) : 0.f;
    }
    __syncthreads();
    if (threadIdx.x < 64) {
      float s = 0.f;
#pragma unroll 8
      for (int c = 0; c < 32; ++c) s += Es[threadIdx.x][c] * ksl[c];
      denl[threadIdx.x] = denl[threadIdx.x] * fsl[threadIdx.x] + s;
    }
    float fr[4];
#pragma unroll
    for (int i = 0; i < 4; ++i) fr[i] = fsl[tn * 4 + i];
#pragma unroll
    for (int i = 0; i < 4; ++i)
#pragma unroll
      for (int j = 0; j < 8; ++j) acc[i][j] *= fr[i];
    for (int m = 0; m < 32; ++m) {
      float e0 = Es[tn * 4 + 0][m];
      float e1 = Es[tn * 4 + 1][m];
      float e2 = Es[tn * 4 + 2][m];
      float e3 = Es[tn * 4 + 3][m];
      float4 c0 = *(const float4*)(&Cs[m][td * 8]);
      float4 c1 = *(const float4*)(&Cs[m][td * 8 + 4]);
      float cv[8] = {c0.x, c0.y, c0.z, c0.w, c1.x, c1.y, c1.z, c1.w};
#pragma unroll
      for (int j = 0; j < 8; ++j) {
        acc[0][j] += e0 * cv[j];
        acc[1][j] += e1 * cv[j];
        acc[2][j] += e2 * cv[j];
        acc[3][j] += e3 * cv[j];
      }
    }
  }
  __syncthreads();
  if (threadIdx.x < 64)
    denl[threadIdx.x] = 1.f / (RATIO_ * (denl[threadIdx.x] + EPS_ * ksumtot[bh]));
  __syncthreads();
#pragma unroll
  for (int i = 0; i < 4; ++i) {
    int r = tn * 4 + i;
    float di = denl[r];
#pragma unroll
    for (int j = 0; j < 8; ++j) {
      int d = td * 8 + j;
      qb[(size_t)r * DH_ + d] = RATIO_ * (acc[i][j] + EPS_ * ctxsum[bh * DH_ + d]) * di;
    }
  }
}

// ------------------- Wo projection + residual + LN2 + FFN + residual
__global__ __launch_bounds__(384) void k_out_ffn(
    const float* __restrict__ attn, const float* __restrict__ Wo,
    const float* __restrict__ bo, const float* __restrict__ g2,
    const float* __restrict__ be2, const float* __restrict__ W1,
    const float* __restrict__ bf1, const float* __restrict__ W2,
    const float* __restrict__ bf2, float* __restrict__ x) {
  int token = blockIdx.x;
  int b = token >> 12, n = token & 4095;
  int c = threadIdx.x;
  int hh = c >> 7, dh = c & 127;
  float a = attn[(((size_t)(b * H_ + hh)) * N_ + n) * DH_ + dh];
  float p0 = a * Wo[c * 3 + 0], p1 = a * Wo[c * 3 + 1], p2 = a * Wo[c * 3 + 2];
#pragma unroll
  for (int off = 32; off > 0; off >>= 1) {
    p0 += __shfl_down(p0, off);
    p1 += __shfl_down(p1, off);
    p2 += __shfl_down(p2, off);
  }
  __shared__ float red[6][3];
  int wv = c >> 6;
  if ((c & 63) == 0) { red[wv][0] = p0; red[wv][1] = p1; red[wv][2] = p2; }
  __syncthreads();
  if (c == 0) {
    float o0 = bo[0], o1 = bo[1], o2 = bo[2];
#pragma unroll
    for (int w = 0; w < 6; ++w) { o0 += red[w][0]; o1 += red[w][1]; o2 += red[w][2]; }
    float x0 = x[(size_t)token * 3 + 0] + o0;
    float x1 = x[(size_t)token * 3 + 1] + o1;
    float x2 = x[(size_t)token * 3 + 2] + o2;
    float mu = (x0 + x1 + x2) * (1.f / 3.f);
    float d0 = x0 - mu, d1 = x1 - mu, d2 = x2 - mu;
    float rs = rsqrtf((d0 * d0 + d1 * d1 + d2 * d2) * (1.f / 3.f) + 1e-5f);
    float h0 = d0 * rs * g2[0] + be2[0];
    float h1 = d1 * rs * g2[1] + be2[1];
    float h2 = d2 * rs * g2[2] + be2[2];
    float y0 = x0 + bf2[0], y1 = x1 + bf2[1], y2 = x2 + bf2[2];
#pragma unroll
    for (int t = 0; t < 12; ++t) {
      float f = h0 * W1[t] + h1 * W1[12 + t] + h2 * W1[24 + t] + bf1[t];
      float g = 0.5f * f * (1.f + erff(f * 0.70710678118654752f));
      y0 += g * W2[t * 3 + 0];
      y1 += g * W2[t * 3 + 1];
      y2 += g * W2[t * 3 + 2];
    }
    x[(size_t)token * 3 + 0] = y0;
    x[(size_t)token * 3 + 1] = y1;
    x[(size_t)token * 3 + 2] = y2;
  }
}

// ---------------------------------------------------------- decoder
__global__ void k_decode(const float* __restrict__ x, const float* __restrict__ dw,
                         const float* __restrict__ db, float* __restrict__ out) {
  int t = blockIdx.x * 256 + threadIdx.x;
  if (t < B_ * N_) {
    float l = x[(size_t)t * 3 + 0] * dw[0] + x[(size_t)t * 3 + 1] * dw[1] +
              x[(size_t)t * 3 + 2] * dw[2] + db[0];
    out[t] = 1.f / (1.f + expf(-l));
  }
}

// ================================================================ launch
extern "C" void kernel_launch(void* const* d_in, const int* in_sizes, int n_in,
                              void* d_out, int out_size, void* d_ws, size_t ws_size,
                              hipStream_t stream) {
  const float* x_in = (const float*)d_in[0];
  const float* Wq = (const float*)d_in[1];
  const float* Wk = (const float*)d_in[2];
  const float* Wv = (const float*)d_in[3];
  const float* Wo = (const float*)d_in[4];
  const float* bo = (const float*)d_in[5];
  const float* ln1g = (const float*)d_in[6];
  const float* ln1b = (const float*)d_in[7];
  const float* W1 = (const float*)d_in[8];
  const float* b1 = (const float*)d_in[9];
  const float* W2 = (const float*)d_in[10];
  const float* b2 = (const float*)d_in[11];
  const float* ln2g = (const float*)d_in[12];
  const float* ln2b = (const float*)d_in[13];
  const float* proj = (const float*)d_in[14];
  const float* dec_w = (const float*)d_in[15];
  const float* dec_b = (const float*)d_in[16];

  const size_t XB = (size_t)B_ * N_ * 3;         // 98304
  const size_t QKV = (size_t)BH_ * N_ * DH_;     // 12582912
  const size_t CTX = (size_t)BH_ * M_ * DH_;     // 1904640
  const size_t SS = (size_t)BH_ * M_;            // 14880
  const size_t VSP = (size_t)8 * BH_ * DH_;      // 24576
  const size_t CS = (size_t)BH_ * DH_;           // 3072

  float* w = (float*)d_ws;
  float* xbuf = w;            w += XB;
  float* q = w;               w += QKV;
  float* k = w;               w += QKV;
  float* v = w;               w += QKV;
  float* C0 = w;              w += 2 * CTX;   // two split-N partials, contiguous
  float* s0 = w;              w += 2 * SS;
  float* ctx = w;             w += CTX;
  float* ksum = w;            w += SS;
  float* vsp = w;             w += VSP;
  float* ctxsum = w;          w += CS;
  float* ksumtot = w;         w += BH_;
  float* blkmax = w;          w += (size_t)BH_ * 64 * 10;
  float* mxb = w;             w += BH_;
  // total ~166.5 MiB of d_ws

  k_copy<<<(XB + 255) / 256, 256, 0, stream>>>(x_in, xbuf, (int)XB);

  for (int i = 0; i < DEPTH_; ++i) {
    const float* pj = proj + (size_t)i * M_ * DH_;
    k_ln_qkv<<<B_ * N_, 384, 0, stream>>>(xbuf, Wq + (size_t)i * 3 * INNER_,
                                          Wk + (size_t)i * 3 * INNER_,
                                          Wv + (size_t)i * 3 * INNER_,
                                          ln1g + i * 3, ln1b + i * 3, q, k, v);
    k_kmax<<<dim3(10, 64, BH_), 256, 0, stream>>>(k, pj, blkmax);
    k_kmax_reduce<<<BH_, 256, 0, stream>>>(blkmax, mxb);
    k_kp_ctx<<<dim3(2, 10, BH_), 256, 0, stream>>>(k, v, pj, mxb, C0, s0);
    k_vsum<<<dim3(8, BH_), 128, 0, stream>>>(v, vsp);
    k_finalize<<<BH_, 128, 0, stream>>>(C0, s0, vsp, ctx, ksum, ctxsum, ksumtot);
    k_q_attn<<<dim3(64, BH_), 256, 0, stream>>>(q, pj, ctx, ksum, ctxsum, ksumtot);
    k_out_ffn<<<B_ * N_, 384, 0, stream>>>(q, Wo + (size_t)i * INNER_ * 3, bo + i * 3,
                                           ln2g + i * 3, ln2b + i * 3,
                                           W1 + (size_t)i * 36, b1 + (size_t)i * 12,
                                           W2 + (size_t)i * 36, b2 + i * 3, xbuf);
  }
  k_decode<<<(B_ * N_ + 255) / 256, 256, 0, stream>>>(xbuf, dec_w, dec_b, (float*)d_out);
}

// Round 2
// 5112.650 us; speedup vs baseline: 2.4456x; 2.4456x over previous
//
#include <hip/hip_runtime.h>
#include <math.h>

// Performer (FAVOR+) forward, 6 layers. bf16 MFMA for all big GEMMs.
// B=8 N=4096 DIM=3 H=3 DH=128 INNER=384 M=620(pad 640) FF=12
#define B_ 8
#define N_ 4096
#define H_ 3
#define DH_ 128
#define INNER_ 384
#define M_ 620
#define MP_ 640
#define DEPTH_ 6
#define BH_ 24

static constexpr float DN_ = 0.29730177875068026f;     // 128^-0.25
static constexpr float RATIO_ = 0.04016096644512494f;  // 620^-0.5
static constexpr float EPS_ = 1e-4f;

typedef __attribute__((ext_vector_type(8))) short short8;
typedef __attribute__((ext_vector_type(4))) float f32x4;

__device__ __forceinline__ short f2bf(float f) {
  union { float f; unsigned u; } x; x.f = f;
  unsigned r = x.u + 0x7FFF + ((x.u >> 16) & 1);
  return (short)(r >> 16);
}
__device__ __forceinline__ float bf2f(short s) {
  union { unsigned u; float f; } x; x.u = ((unsigned)(unsigned short)s) << 16;
  return x.f;
}
__device__ __forceinline__ float4 ldg4(const float* p) { return *(const float4*)p; }

// ---------------------------------------------------------------- copy
__global__ void k_copy(const float* __restrict__ s, float* __restrict__ d, int n) {
  int i = blockIdx.x * 256 + threadIdx.x;
  if (i < n) d[i] = s[i];
}

// ------------------------------------------- proj -> bf16, padded to 640 rows
__global__ void k_projcvt(const float* __restrict__ proj, short* __restrict__ pb) {
  int i = blockIdx.x * 256 + threadIdx.x;
  if (i >= DEPTH_ * MP_ * DH_) return;
  int l = i / (MP_ * DH_);
  int rem = i - l * (MP_ * DH_);
  int m = rem >> 7, d = rem & 127;
  pb[i] = (m < M_) ? f2bf(proj[((size_t)l * M_ + m) * DH_ + d]) : (short)0;
}

// ------------------------------------------------- LN1 + QKV projection
// grid B*N blocks, 384 threads. q,k stored pre-scaled by DN_, bf16. diag fp32.
__global__ __launch_bounds__(384) void k_ln_qkv(
    const float* __restrict__ x, const float* __restrict__ Wq,
    const float* __restrict__ Wk, const float* __restrict__ Wv,
    const float* __restrict__ g1, const float* __restrict__ b1,
    short* __restrict__ qb, short* __restrict__ kb, short* __restrict__ vb,
    float* __restrict__ diag_q, float* __restrict__ diag_k) {
  int token = blockIdx.x;
  int b = token >> 12, n = token & 4095;
  int c = threadIdx.x;
  float x0 = x[(size_t)token * 3 + 0];
  float x1 = x[(size_t)token * 3 + 1];
  float x2 = x[(size_t)token * 3 + 2];
  float mu = (x0 + x1 + x2) * (1.f / 3.f);
  float d0 = x0 - mu, d1 = x1 - mu, d2 = x2 - mu;
  float rs = rsqrtf((d0 * d0 + d1 * d1 + d2 * d2) * (1.f / 3.f) + 1e-5f);
  float h0 = d0 * rs * g1[0] + b1[0];
  float h1 = d1 * rs * g1[1] + b1[1];
  float h2 = d2 * rs * g1[2] + b1[2];
  float qv = (h0 * Wq[c] + h1 * Wq[INNER_ + c] + h2 * Wq[2 * INNER_ + c]) * DN_;
  float kv = (h0 * Wk[c] + h1 * Wk[INNER_ + c] + h2 * Wk[2 * INNER_ + c]) * DN_;
  float vv = h0 * Wv[c] + h1 * Wv[INNER_ + c] + h2 * Wv[2 * INNER_ + c];
  int hh = c >> 7, dh = c & 127;
  size_t idx = (((size_t)(b * H_ + hh)) * N_ + n) * DH_ + dh;
  qb[idx] = f2bf(qv);
  kb[idx] = f2bf(kv);
  vb[idx] = f2bf(vv);
  float q2 = qv * qv, k2 = kv * kv;
#pragma unroll
  for (int off = 32; off; off >>= 1) {
    q2 += __shfl_down(q2, off);
    k2 += __shfl_down(k2, off);
  }
  __shared__ float sq[6], sk[6];
  if ((c & 63) == 0) { sq[c >> 6] = q2; sk[c >> 6] = k2; }
  __syncthreads();
  if ((c & 127) == 0) {
    int h2i = c >> 7;
    size_t di = (size_t)(b * H_ + h2i) * N_ + n;
    diag_q[di] = 0.5f * (sq[2 * h2i] + sq[2 * h2i + 1]);
    diag_k[di] = 0.5f * (sk[2 * h2i] + sk[2 * h2i + 1]);
  }
}

// ------------------------------------------------- key-side global max (MFMA)
// grid (32 nt, 24 bh), 512 threads (8 waves, 16 n-rows each).
__global__ __launch_bounds__(512) void k_kmax(
    const short* __restrict__ kb, const short* __restrict__ pb,
    float* __restrict__ blkmax) {
  int nt = blockIdx.x, bh = blockIdx.y;
  __shared__ short K_s[128 * 128];
  __shared__ float red[8];
  int t = threadIdx.x, w = t >> 6, l = t & 63, lr = l & 15, lg = l >> 4;
  {
    int n = t >> 2, seg = t & 3;
    const short* src = kb + ((size_t)bh * N_ + nt * 128 + n) * DH_ + seg * 32;
#pragma unroll
    for (int j = 0; j < 4; ++j) {
      short8 v8 = *(const short8*)(src + j * 8);
      int d0 = seg * 32 + j * 8;
      int ofs = (n * 256 + d0 * 2) ^ ((n & 7) << 4);
      *(short8*)((char*)K_s + ofs) = v8;
    }
  }
  __syncthreads();
  short8 afr[4];
  {
    int row = w * 16 + lr;
#pragma unroll
    for (int ks = 0; ks < 4; ++ks) {
      int d0 = ks * 32 + lg * 8;
      int ofs = (row * 256 + d0 * 2) ^ ((row & 7) << 4);
      afr[ks] = *(const short8*)((const char*)K_s + ofs);
    }
  }
  float vmax = -INFINITY;
  for (int mc = 0; mc < 20; ++mc) {
#pragma unroll
    for (int ms = 0; ms < 2; ++ms) {
      int m = mc * 32 + ms * 16 + lr;
      const short* bp = pb + (size_t)m * DH_ + lg * 8;
      f32x4 acc = {0.f, 0.f, 0.f, 0.f};
#pragma unroll
      for (int ks = 0; ks < 4; ++ks)
        acc = __builtin_amdgcn_mfma_f32_16x16x32_bf16(
            afr[ks], *(const short8*)(bp + ks * 32), acc, 0, 0, 0);
      if (m < M_)
        vmax = fmaxf(vmax, fmaxf(fmaxf(acc[0], acc[1]), fmaxf(acc[2], acc[3])));
    }
  }
#pragma unroll
  for (int off = 1; off < 64; off <<= 1) vmax = fmaxf(vmax, __shfl_xor(vmax, off));
  if (l == 0) red[w] = vmax;
  __syncthreads();
  if (t == 0) {
    float m = red[0];
#pragma unroll
    for (int i = 1; i < 8; ++i) m = fmaxf(m, red[i]);
    blkmax[bh * 32 + nt] = m;
  }
}

__global__ void k_kmax_reduce(const float* __restrict__ blkmax, float* __restrict__ mx) {
  int bh = blockIdx.x, l = threadIdx.x;
  float m = (l < 32) ? blkmax[bh * 32 + l] : -INFINITY;
#pragma unroll
  for (int off = 32; off; off >>= 1) m = fmaxf(m, __shfl_down(m, off));
  if (l == 0) mx[bh] = m;
}

// ---------------------------------------- key features -> ctx partials (MFMA)
// grid (4 ns, 5 mt, 24 bh), 512 threads. Each wave: 16 m-cols, all d.
__global__ __launch_bounds__(512) void k_kp_ctx(
    const short* __restrict__ kb, const short* __restrict__ vb,
    const short* __restrict__ pb, const float* __restrict__ diag_k,
    const float* __restrict__ mxb,
    float* __restrict__ Cpart, float* __restrict__ spart) {
  int ns = blockIdx.x, mt = blockIdx.y, bh = blockIdx.z;
  __shared__ short K_s[32 * 128];
  __shared__ short Vt_s[128 * 40];
  __shared__ float diag_s[32];
  int t = threadIdx.x, w = t >> 6, l = t & 63, lr = l & 15, lg = l >> 4;
  float mxv = mxb[bh];
  int m0 = mt * 128 + w * 16;
  short8 bfr[4];
  {
    const short* pr = pb + (size_t)(m0 + lr) * DH_ + lg * 8;
#pragma unroll
    for (int ks = 0; ks < 4; ++ks) bfr[ks] = *(const short8*)(pr + ks * 32);
  }
  f32x4 cacc[8];
#pragma unroll
  for (int db = 0; db < 8; ++db) cacc[db] = (f32x4){0.f, 0.f, 0.f, 0.f};
  float ksacc = 0.f;
  const short* kbase = kb + ((size_t)bh * N_ + ns * 1024) * DH_;
  const short* vbase = vb + ((size_t)bh * N_ + ns * 1024) * DH_;
  const float* dbase = diag_k + (size_t)bh * N_ + ns * 1024;
  int sn = t >> 4, sd0 = (t & 15) * 8;
  int spi = ((sn >> 2) & 3) * 8 + ((sn >> 4) & 1) * 4 + (sn & 3);  // pi(n)
  for (int ch = 0; ch < 32; ++ch) {
    __syncthreads();
    {
      short8 k8 = *(const short8*)(kbase + (size_t)(ch * 32 + sn) * DH_ + sd0);
      int ofs = (sn * 256 + sd0 * 2) ^ ((sn & 7) << 4);
      *(short8*)((char*)K_s + ofs) = k8;
      short8 v8 = *(const short8*)(vbase + (size_t)(ch * 32 + sn) * DH_ + sd0);
#pragma unroll
      for (int j = 0; j < 8; ++j) Vt_s[(sd0 + j) * 40 + spi] = v8[j];
      if (t < 32) diag_s[t] = dbase[ch * 32 + t];
    }
    __syncthreads();
    float Ev[8];
    short8 ea;
#pragma unroll
    for (int nsub = 0; nsub < 2; ++nsub) {
      int r = nsub * 16 + lr;
      f32x4 acc = {0.f, 0.f, 0.f, 0.f};
#pragma unroll
      for (int ks = 0; ks < 4; ++ks) {
        int d0 = ks * 32 + lg * 8;
        int ofs = (r * 256 + d0 * 2) ^ ((r & 7) << 4);
        acc = __builtin_amdgcn_mfma_f32_16x16x32_bf16(
            *(const short8*)((const char*)K_s + ofs), bfr[ks], acc, 0, 0, 0);
      }
#pragma unroll
      for (int rg = 0; rg < 4; ++rg) {
        float e = __expf(acc[rg] - diag_s[nsub * 16 + 4 * lg + rg] - mxv);
        Ev[nsub * 4 + rg] = e;
        ea[nsub * 4 + rg] = f2bf(e);
        ksacc += e;
      }
    }
#pragma unroll
    for (int db = 0; db < 8; ++db) {
      short8 b2 = *(const short8*)&Vt_s[(db * 16 + lr) * 40 + lg * 8];
      cacc[db] = __builtin_amdgcn_mfma_f32_16x16x32_bf16(ea, b2, cacc[db], 0, 0, 0);
    }
  }
  float* Cp = Cpart + ((size_t)ns * BH_ + bh) * MP_ * DH_;
#pragma unroll
  for (int db = 0; db < 8; ++db) {
    int d = db * 16 + lr;
#pragma unroll
    for (int rg = 0; rg < 4; ++rg)
      Cp[(size_t)(m0 + 4 * lg + rg) * DH_ + d] = cacc[db][rg];
  }
  ksacc += __shfl_down(ksacc, 32);
  ksacc += __shfl_down(ksacc, 16);
  if (l < 16) spart[((size_t)ns * BH_ + bh) * MP_ + m0 + l] = ksacc;
}

// v column-sum partials: grid (8 ns, 24 bh), 128 threads
__global__ __launch_bounds__(128) void k_vsum(
    const short* __restrict__ vb, float* __restrict__ vsp) {
  int ns = blockIdx.x, bh = blockIdx.y, d = threadIdx.x;
  const short* v2 = vb + ((size_t)bh * N_ + ns * 512) * DH_ + d;
  float s = 0.f;
  for (int n = 0; n < 512; ++n) s += bf2f(v2[(size_t)n * DH_]);
  vsp[((size_t)ns * BH_ + bh) * DH_ + d] = s;
}

// finalize ctx / k_sum (+EPS terms, ratio, zero pad rows), ctxsum, ksumtot
__global__ __launch_bounds__(128) void k_finalize(
    const float* __restrict__ Cpart, const float* __restrict__ spart,
    const float* __restrict__ vsp,
    float* __restrict__ ctx, float* __restrict__ ksum,
    float* __restrict__ ctxsum, float* __restrict__ ksumtot) {
  int bh = blockIdx.x, d = threadIdx.x;
  float vsv = 0.f;
#pragma unroll
  for (int ns = 0; ns < 8; ++ns) vsv += vsp[((size_t)ns * BH_ + bh) * DH_ + d];
  vsv *= EPS_;
  const size_t ph = (size_t)BH_ * MP_ * DH_;
  const float* c0 = Cpart + (size_t)bh * MP_ * DH_;
  float* cx = ctx + (size_t)bh * MP_ * DH_;
  float csum = 0.f;
  for (int m = 0; m < MP_; ++m) {
    float c = 0.f;
    if (m < M_) {
      size_t o = (size_t)m * DH_ + d;
      c = RATIO_ * (c0[o] + c0[o + ph] + c0[o + 2 * ph] + c0[o + 3 * ph] + vsv);
    }
    cx[(size_t)m * DH_ + d] = c;
    csum += c;
  }
  ctxsum[bh * DH_ + d] = csum;
  __shared__ float red[128];
  float kt = 0.f;
  for (int m = d; m < MP_; m += 128) {
    float ks = 0.f;
    if (m < M_) {
      size_t o = (size_t)bh * MP_ + m;
      size_t sh = (size_t)BH_ * MP_;
      ks = RATIO_ * (spart[o] + spart[o + sh] + spart[o + 2 * sh] + spart[o + 3 * sh] +
                     EPS_ * (float)N_);
    }
    ksum[(size_t)bh * MP_ + m] = ks;
    kt += ks;
  }
  red[d] = kt;
  __syncthreads();
  for (int s = 64; s > 0; s >>= 1) {
    if (d < s) red[d] += red[d + s];
    __syncthreads();
  }
  if (d == 0) ksumtot[bh] = red[0];
}

// ------------------------- query side (MFMA): 2-pass row-max, E@ctx, write o
// grid (32 nt, 24 bh), 512 threads.
__global__ __launch_bounds__(512) void k_q_attn(
    const short* __restrict__ qb, const short* __restrict__ pb,
    const float* __restrict__ ctx, const float* __restrict__ ksum,
    const float* __restrict__ diag_q, const float* __restrict__ ctxsum,
    const float* __restrict__ ksumtot, float* __restrict__ o) {
  int nt = blockIdx.x, bh = blockIdx.y;
  __shared__ short Q_s[128 * 128];
  __shared__ short ctxT_s[128 * 40];
  __shared__ float ksl[32];
  int t = threadIdx.x, w = t >> 6, l = t & 63, lr = l & 15, lg = l >> 4;
  {
    int n = t >> 2, seg = t & 3;
    const short* src = qb + ((size_t)bh * N_ + nt * 128 + n) * DH_ + seg * 32;
#pragma unroll
    for (int j = 0; j < 4; ++j) {
      short8 v8 = *(const short8*)(src + j * 8);
      int d0 = seg * 32 + j * 8;
      int ofs = (n * 256 + d0 * 2) ^ ((n & 7) << 4);
      *(short8*)((char*)Q_s + ofs) = v8;
    }
  }
  __syncthreads();
  short8 qfr[4];
  {
    int row = w * 16 + lr;
#pragma unroll
    for (int ks = 0; ks < 4; ++ks) {
      int d0 = ks * 32 + lg * 8;
      int ofs = (row * 256 + d0 * 2) ^ ((row & 7) << 4);
      qfr[ks] = *(const short8*)((const char*)Q_s + ofs);
    }
  }
  float dq = diag_q[(size_t)bh * N_ + nt * 128 + w * 16 + lr];
  // pass 1: per-row max of dd over valid m
  float vmax = -INFINITY;
  for (int mc = 0; mc < 20; ++mc) {
#pragma unroll
    for (int ms = 0; ms < 2; ++ms) {
      const short* ap = pb + (size_t)(mc * 32 + ms * 16 + lr) * DH_ + lg * 8;
      f32x4 acc = {0.f, 0.f, 0.f, 0.f};
#pragma unroll
      for (int ks = 0; ks < 4; ++ks)
        acc = __builtin_amdgcn_mfma_f32_16x16x32_bf16(
            *(const short8*)(ap + ks * 32), qfr[ks], acc, 0, 0, 0);
#pragma unroll
      for (int rg = 0; rg < 4; ++rg) {
        int mg = mc * 32 + ms * 16 + 4 * lg + rg;
        if (mg < M_) vmax = fmaxf(vmax, acc[rg]);
      }
    }
  }
  vmax = fmaxf(vmax, __shfl_xor(vmax, 16));
  vmax = fmaxf(vmax, __shfl_xor(vmax, 32));
  // pass 2
  f32x4 cacc[8];
#pragma unroll
  for (int db = 0; db < 8; ++db) cacc[db] = (f32x4){0.f, 0.f, 0.f, 0.f};
  float den = 0.f;
  int sm = t >> 4, sd0 = (t & 15) * 8;
  int spi = ((sm >> 2) & 3) * 8 + ((sm >> 4) & 1) * 4 + (sm & 3);
  for (int mc = 0; mc < 20; ++mc) {
    __syncthreads();
    {
      const float* cp = ctx + ((size_t)bh * MP_ + mc * 32 + sm) * DH_ + sd0;
      float4 c0 = ldg4(cp);
      float4 c1 = ldg4(cp + 4);
      ctxT_s[(sd0 + 0) * 40 + spi] = f2bf(c0.x);
      ctxT_s[(sd0 + 1) * 40 + spi] = f2bf(c0.y);
      ctxT_s[(sd0 + 2) * 40 + spi] = f2bf(c0.z);
      ctxT_s[(sd0 + 3) * 40 + spi] = f2bf(c0.w);
      ctxT_s[(sd0 + 4) * 40 + spi] = f2bf(c1.x);
      ctxT_s[(sd0 + 5) * 40 + spi] = f2bf(c1.y);
      ctxT_s[(sd0 + 6) * 40 + spi] = f2bf(c1.z);
      ctxT_s[(sd0 + 7) * 40 + spi] = f2bf(c1.w);
      if (t < 32) ksl[t] = ksum[(size_t)bh * MP_ + mc * 32 + t];
    }
    __syncthreads();
    float Ev[8];
    short8 ea;
#pragma unroll
    for (int ms = 0; ms < 2; ++ms) {
      const short* ap = pb + (size_t)(mc * 32 + ms * 16 + lr) * DH_ + lg * 8;
      f32x4 acc = {0.f, 0.f, 0.f, 0.f};
#pragma unroll
      for (int ks = 0; ks < 4; ++ks)
        acc = __builtin_amdgcn_mfma_f32_16x16x32_bf16(
            *(const short8*)(ap + ks * 32), qfr[ks], acc, 0, 0, 0);
#pragma unroll
      for (int rg = 0; rg < 4; ++rg) {
        float e = __expf(acc[rg] - dq - vmax);
        Ev[ms * 4 + rg] = e;
        ea[ms * 4 + rg] = f2bf(e);
      }
    }
#pragma unroll
    for (int s = 0; s < 8; ++s) {
      int ml = ((s >> 2) << 4) + 4 * lg + (s & 3);
      den += Ev[s] * ksl[ml];
    }
#pragma unroll
    for (int db = 0; db < 8; ++db) {
      short8 b2 = *(const short8*)&ctxT_s[(db * 16 + lr) * 40 + lg * 8];
      cacc[db] = __builtin_amdgcn_mfma_f32_16x16x32_bf16(ea, b2, cacc[db], 0, 0, 0);
    }
  }
  den += __shfl_down(den, 32);
  den += __shfl_down(den, 16);  // lanes 0..15: den for n = lr
  float kst = ksumtot[bh];
  float dinv[4];
#pragma unroll
  for (int rg = 0; rg < 4; ++rg) {
    float dn2 = __shfl(den, 4 * lg + rg);
    dinv[rg] = 1.f / (RATIO_ * (dn2 + EPS_ * kst));
  }
  float* ob = o + ((size_t)bh * N_ + nt * 128 + w * 16) * DH_;
#pragma unroll
  for (int db = 0; db < 8; ++db) {
    int d = db * 16 + lr;
    float cs = ctxsum[bh * DH_ + d] * EPS_;
#pragma unroll
    for (int rg = 0; rg < 4; ++rg)
      ob[(size_t)(4 * lg + rg) * DH_ + d] = RATIO_ * (cacc[db][rg] + cs) * dinv[rg];
  }
}

// ------------------- Wo projection + residual + LN2 + FFN + residual
__global__ __launch_bounds__(384) void k_out_ffn(
    const float* __restrict__ attn, const float* __restrict__ Wo,
    const float* __restrict__ bo, const float* __restrict__ g2,
    const float* __restrict__ be2, const float* __restrict__ W1,
    const float* __restrict__ bf1, const float* __restrict__ W2,
    const float* __restrict__ bf2, float* __restrict__ x) {
  int token = blockIdx.x;
  int b = token >> 12, n = token & 4095;
  int c = threadIdx.x;
  int hh = c >> 7, dh = c & 127;
  float a = attn[(((size_t)(b * H_ + hh)) * N_ + n) * DH_ + dh];
  float p0 = a * Wo[c * 3 + 0], p1 = a * Wo[c * 3 + 1], p2 = a * Wo[c * 3 + 2];
#pragma unroll
  for (int off = 32; off > 0; off >>= 1) {
    p0 += __shfl_down(p0, off);
    p1 += __shfl_down(p1, off);
    p2 += __shfl_down(p2, off);
  }
  __shared__ float red[6][3];
  int wv = c >> 6;
  if ((c & 63) == 0) { red[wv][0] = p0; red[wv][1] = p1; red[wv][2] = p2; }
  __syncthreads();
  if (c == 0) {
    float o0 = bo[0], o1 = bo[1], o2 = bo[2];
#pragma unroll
    for (int w = 0; w < 6; ++w) { o0 += red[w][0]; o1 += red[w][1]; o2 += red[w][2]; }
    float x0 = x[(size_t)token * 3 + 0] + o0;
    float x1 = x[(size_t)token * 3 + 1] + o1;
    float x2 = x[(size_t)token * 3 + 2] + o2;
    float mu = (x0 + x1 + x2) * (1.f / 3.f);
    float d0 = x0 - mu, d1 = x1 - mu, d2 = x2 - mu;
    float rs = rsqrtf((d0 * d0 + d1 * d1 + d2 * d2) * (1.f / 3.f) + 1e-5f);
    float h0 = d0 * rs * g2[0] + be2[0];
    float h1 = d1 * rs * g2[1] + be2[1];
    float h2 = d2 * rs * g2[2] + be2[2];
    float y0 = x0 + bf2[0], y1 = x1 + bf2[1], y2 = x2 + bf2[2];
#pragma unroll
    for (int tt = 0; tt < 12; ++tt) {
      float f = h0 * W1[tt] + h1 * W1[12 + tt] + h2 * W1[24 + tt] + bf1[tt];
      float g = 0.5f * f * (1.f + erff(f * 0.70710678118654752f));
      y0 += g * W2[tt * 3 + 0];
      y1 += g * W2[tt * 3 + 1];
      y2 += g * W2[tt * 3 + 2];
    }
    x[(size_t)token * 3 + 0] = y0;
    x[(size_t)token * 3 + 1] = y1;
    x[(size_t)token * 3 + 2] = y2;
  }
}

// ---------------------------------------------------------- decoder
__global__ void k_decode(const float* __restrict__ x, const float* __restrict__ dw,
                         const float* __restrict__ db, float* __restrict__ out) {
  int t = blockIdx.x * 256 + threadIdx.x;
  if (t < B_ * N_) {
    float l = x[(size_t)t * 3 + 0] * dw[0] + x[(size_t)t * 3 + 1] * dw[1] +
              x[(size_t)t * 3 + 2] * dw[2] + db[0];
    out[t] = 1.f / (1.f + expf(-l));
  }
}

// ================================================================ launch
extern "C" void kernel_launch(void* const* d_in, const int* in_sizes, int n_in,
                              void* d_out, int out_size, void* d_ws, size_t ws_size,
                              hipStream_t stream) {
  const float* x_in = (const float*)d_in[0];
  const float* Wq = (const float*)d_in[1];
  const float* Wk = (const float*)d_in[2];
  const float* Wv = (const float*)d_in[3];
  const float* Wo = (const float*)d_in[4];
  const float* bo = (const float*)d_in[5];
  const float* ln1g = (const float*)d_in[6];
  const float* ln1b = (const float*)d_in[7];
  const float* W1 = (const float*)d_in[8];
  const float* b1 = (const float*)d_in[9];
  const float* W2 = (const float*)d_in[10];
  const float* b2 = (const float*)d_in[11];
  const float* ln2g = (const float*)d_in[12];
  const float* ln2b = (const float*)d_in[13];
  const float* proj = (const float*)d_in[14];
  const float* dec_w = (const float*)d_in[15];
  const float* dec_b = (const float*)d_in[16];

  const size_t XB = (size_t)B_ * N_ * 3;
  const size_t QKV = (size_t)BH_ * N_ * DH_;       // 12582912
  const size_t CTX = (size_t)BH_ * MP_ * DH_;      // 1966080
  const size_t SS = (size_t)BH_ * MP_;

  char* p = (char*)d_ws;
  auto alloc = [&](size_t bytes) {
    char* r = p;
    p += (bytes + 255) & ~(size_t)255;
    return r;
  };
  float* xbuf = (float*)alloc(XB * 4);
  short* qb = (short*)alloc(QKV * 2);
  short* kb = (short*)alloc(QKV * 2);
  short* vb = (short*)alloc(QKV * 2);
  float* diag_q = (float*)alloc((size_t)BH_ * N_ * 4);
  float* diag_k = (float*)alloc((size_t)BH_ * N_ * 4);
  short* pb = (short*)alloc((size_t)DEPTH_ * MP_ * DH_ * 2);
  // o (50.3MB) and Cpart (31.5MB) have disjoint lifetimes -> alias
  float* o = (float*)alloc(QKV * 4);
  float* Cpart = o;
  float* spart = (float*)alloc(4 * SS * 4);
  float* ctx = (float*)alloc(CTX * 4);
  float* ksum = (float*)alloc(SS * 4);
  float* vsp = (float*)alloc((size_t)8 * BH_ * DH_ * 4);
  float* ctxsum = (float*)alloc((size_t)BH_ * DH_ * 4);
  float* ksumtot = (float*)alloc(BH_ * 4);
  float* blkmax = (float*)alloc((size_t)BH_ * 32 * 4);
  float* mxb = (float*)alloc(BH_ * 4);

  k_copy<<<(XB + 255) / 256, 256, 0, stream>>>(x_in, xbuf, (int)XB);
  k_projcvt<<<(DEPTH_ * MP_ * DH_ + 255) / 256, 256, 0, stream>>>(proj, pb);

  for (int i = 0; i < DEPTH_; ++i) {
    const short* pbL = pb + (size_t)i * MP_ * DH_;
    k_ln_qkv<<<B_ * N_, 384, 0, stream>>>(xbuf, Wq + (size_t)i * 3 * INNER_,
                                          Wk + (size_t)i * 3 * INNER_,
                                          Wv + (size_t)i * 3 * INNER_,
                                          ln1g + i * 3, ln1b + i * 3,
                                          qb, kb, vb, diag_q, diag_k);
    k_kmax<<<dim3(32, BH_), 512, 0, stream>>>(kb, pbL, blkmax);
    k_kmax_reduce<<<BH_, 64, 0, stream>>>(blkmax, mxb);
    k_kp_ctx<<<dim3(4, 5, BH_), 512, 0, stream>>>(kb, vb, pbL, diag_k, mxb, Cpart, spart);
    k_vsum<<<dim3(8, BH_), 128, 0, stream>>>(vb, vsp);
    k_finalize<<<BH_, 128, 0, stream>>>(Cpart, spart, vsp, ctx, ksum, ctxsum, ksumtot);
    k_q_attn<<<dim3(32, BH_), 512, 0, stream>>>(qb, pbL, ctx, ksum, diag_q, ctxsum,
                                                ksumtot, o);
    k_out_ffn<<<B_ * N_, 384, 0, stream>>>(o, Wo + (size_t)i * INNER_ * 3, bo + i * 3,
                                           ln2g + i * 3, ln2b + i * 3,
                                           W1 + (size_t)i * 36, b1 + (size_t)i * 12,
                                           W2 + (size_t)i * 36, b2 + i * 3, xbuf);
  }
  k_decode<<<(B_ * N_ + 255) / 256, 256, 0, stream>>>(xbuf, dec_w, dec_b, (float*)d_out);
}